// Round 5
// baseline (863.492 us; speedup 1.0000x reference)
//
#include <hip/hip_runtime.h>

// PRNNLayer: B=4096 chains x T=2048 steps, 5 states.
// R7: single kernel. 4 role-waves per 256-thread block (one SIMD each):
//   role0: s0   role1: s1+s3 (critical)   role2: s2   role3: s4
// Roles write the AoS output DIRECTLY (4B dwords at stride 20B), with one raw
// s_barrier per chunk to pace the waves to <=16-step skew so all 5 dwords of
// each 80B line land in the same CU's L2 within a ~3us window and merge
// (R5 showed unpaced roles desync by whole chains -> 3.7x write amp; R4
// showed __syncthreads' vmcnt(0) drain is too expensive -- raw s_barrier has
// neither problem; it is purely advisory, no cross-wave data deps exist).
// This deletes R6's tx transpose pass (~80us) and its workspace round-trip.
// All state-update arithmetic verbatim from the verified R5/R6 kernels.

#define NB 4096
#define NT 2048
#define CHUNK 16
#define NCHUNK (NT / CHUNK)  // 128

#define L2E10 14.4269504089f  // 10*log2(e)  (hv(x) = sigmoid(10x))
#define L2E    1.44269504089f

__device__ __forceinline__ float rcpf(float x) { return __builtin_amdgcn_rcpf(x); }
__device__ __forceinline__ float ex2(float a)  { return __builtin_amdgcn_exp2f(a); }
__device__ __forceinline__ float ex2c(float a) { return __builtin_amdgcn_exp2f(fminf(a, 80.0f)); }
__device__ __forceinline__ float clip1e5(float x) {
    return __builtin_amdgcn_fmed3f(x, -100000.0f, 100000.0f);
}

__global__ __launch_bounds__(256, 1)
void prnn_kernel(const float* __restrict__ inp, const float* __restrict__ theta,
                 float* __restrict__ out) {
    const int lane = threadIdx.x & 63;
    const int role = threadIdx.x >> 6;
    const int b = blockIdx.x * 64 + lane;

    // ---- theta (uniform); each role uses a subset, rest DCE'd ----
    const float f_     = theta[0] * 0.1f;
    const float smax_  = theta[1] * 1950.0f;
    const float qmax_  = theta[2] * 50.0f;
    const float ddf_   = theta[3] * 5.0f;
    const float tmin_  = theta[4] * -3.0f;
    const float tmax_  = theta[5] * 3.0f;
    const float Kc_    = theta[6] * 0.5f;
    const float SCmax_ = theta[7] * 1.5f;
    const float spmax_ = theta[8] * 1950.0f;
    const float qpmax_ = theta[9] * 40.0f;
    const float kp     = theta[10];
    const float sgmax_ = theta[11] * 1950.0f;
    const float qgmax_ = theta[12] * 40.0f;
    const float Kl_    = theta[13] * 0.5f;
    const float Kn_    = theta[14] * 0.5f;

    const float inv_smax = rcpf(smax_);
    const float KcDc  = Kc_ * 0.849932f;          // Kc_ * 0.986*0.862
    const float c_sn  = -L2E10 * tmin_;
    const float c_m   =  L2E10 * tmax_;
    const float c_dd  = -ddf_ * tmax_;
    const float c_sc1 =  L2E10 * SCmax_ * 1.4f;
    const float c_sc0 =  L2E10 * SCmax_ * 0.6f;
    const float c_2p  =  L2E10 * spmax_;
    const float c_3s  =  L2E10 * smax_;
    const float c_4s  =  L2E10 * sgmax_;
    const float fE    = f_ * L2E;
    const float c_E2  = -fE * spmax_;
    const float c_E3  = -fE * smax_;
    const float c_E4  = -fE * sgmax_;

    const float* ip = inp + (size_t)b * (NT * 3);
    float*       op = out + (size_t)b * (NT * 5);

    if (role == 0) {
        // ---- s0 ----
        float s0 = 0.f;
        float bA[CHUNK * 3], bB[CHUNK * 3];
        auto pf = [&](float* d, int c) {
            const float4* s = (const float4*)(ip + (size_t)c * (CHUNK * 3));
            #pragma unroll
            for (int i = 0; i < (CHUNK * 3) / 4; ++i) ((float4*)d)[i] = s[i];
        };
        auto cw = [&](const float* d, int c) {
            #pragma unroll
            for (int i = 0; i < CHUNK; ++i) {
                const float p  = d[i * 3 + 0];
                const float dl = d[i * 3 + 2];
                const float day = rcpf(1.0f + ex2(fmaf(-L2E10, dl, 7.21347520f)));
                const float da  = 1.0f + ex2(fmaf(-L2E10, p, L2E));
                const float lai   = fmaf(0.328f, day, 0.15f);
                const float kcf   = fmaf(0.6f, day, 0.4f);
                const float kterm = KcDc * kcf * lai;
                const float zday  = fmaf(c_sc1, day, c_sc0);
                const float e0  = ex2(-L2E10 * s0);
                const float esc = ex2(fmaf(-L2E10, s0, zday));
                const float d0  = 1.0f + e0;
                const float dsc = 1.0f + esc;
                const float Rp  = rcpf(da * d0 * dsc);
                const float pintc = Rp * fmaf(d0 * esc, kterm, p);
                s0 += clip1e5(pintc);
                op[(c * CHUNK + i) * 5 + 0] = s0;
            }
        };
        pf(bA, 0);
        for (int c = 0; c < NCHUNK; c += 2) {
            pf(bB, c + 1);
            cw(bA, c);
            __builtin_amdgcn_s_barrier();
            if (c + 2 < NCHUNK) pf(bA, c + 2);
            cw(bB, c + 1);
            __builtin_amdgcn_s_barrier();
        }
    } else if (role == 1) {
        // ---- s1 + s3 (critical role) ----
        float s1 = 0.f, s3 = 0.f;
        float bA[CHUNK * 3], bB[CHUNK * 3];
        auto pf = [&](float* d, int c) {
            const float4* s = (const float4*)(ip + (size_t)c * (CHUNK * 3));
            #pragma unroll
            for (int i = 0; i < (CHUNK * 3) / 4; ++i) ((float4*)d)[i] = s[i];
        };
        auto cw = [&](const float* d, int c) {
            #pragma unroll
            for (int i = 0; i < CHUNK; ++i) {
                const float p  = d[i * 3 + 0];
                const float tm = d[i * 3 + 1];
                const float dl = d[i * 3 + 2];
                const float A1 = tm + 237.3f;
                const float A2 = tm + 273.2f;
                const float q  = rcpf(A1 * A2);
                const float pe = 436.98672f * dl * ex2(24.958624f * tm * (q * A2)) * (q * A1);
                const float psnow = rcpf(1.0f + ex2(fmaf(L2E10, tm, c_sn))) * p;
                const float dm = 1.0f + ex2(fmaf(-L2E10, tm, c_m));
                const float prain = p - psnow;
                const float e1 = ex2(-L2E10 * s1);
                const float melt = rcpf(dm * (1.0f + e1))
                                   * fminf(s1, fmaf(ddf_, tm, c_dd));
                const float e3  = ex2(-L2E10 * s3);
                const float e3s = ex2c(fmaf(-L2E10, s3, c_3s));
                const float R3  = rcpf((1.0f + e3) * (1.0f + e3s));
                const float E3  = ex2(fmaf(fE, s3, c_E3));
                const float t_et = pe * fmaf(e3s * s3, inv_smax, 1.0f);
                const float t_qs = qmax_ * fmaf(e3s, E3, 1.0f);
                const float outflux = R3 * (t_et + t_qs + (s3 - smax_));
                const float ds3 = prain + melt - outflux;
                s1 += clip1e5(psnow - melt);
                s3 += clip1e5(ds3);
                const int t = c * CHUNK + i;
                op[t * 5 + 1] = s1;
                op[t * 5 + 3] = s3;
            }
        };
        pf(bA, 0);
        for (int c = 0; c < NCHUNK; c += 2) {
            pf(bB, c + 1);
            cw(bA, c);
            __builtin_amdgcn_s_barrier();
            if (c + 2 < NCHUNK) pf(bA, c + 2);
            cw(bB, c + 1);
            __builtin_amdgcn_s_barrier();
        }
    } else if (role == 2) {
        // ---- s2 ----
        float s2 = 0.f;
        float pA[CHUNK], pB[CHUNK];
        auto pf = [&](float* P, int c) {
            #pragma unroll
            for (int i = 0; i < CHUNK; ++i) P[i] = ip[(c * CHUNK + i) * 3 + 0];
        };
        auto cw = [&](const float* P, int c) {
            #pragma unroll
            for (int i = 0; i < CHUNK; ++i) {
                const float p = P[i];
                const float e2  = ex2(-L2E10 * s2);
                const float e2p = ex2c(fmaf(-L2E10, s2, c_2p));
                const float R2  = rcpf((1.0f + e2) * (1.0f + e2p));
                const float E2  = ex2(fmaf(fE, s2, c_E2));
                const float qpref = R2 * fmaf(e2p * E2, kp * p, qpmax_);
                s2 += clip1e5(qpref);
                op[(c * CHUNK + i) * 5 + 2] = s2;
            }
        };
        pf(pA, 0);
        for (int c = 0; c < NCHUNK; c += 2) {
            pf(pB, c + 1);
            cw(pA, c);
            __builtin_amdgcn_s_barrier();
            if (c + 2 < NCHUNK) pf(pA, c + 2);
            cw(pB, c + 1);
            __builtin_amdgcn_s_barrier();
        }
    } else {
        // ---- s4 ----
        float s4 = 0.f;
        float pA[CHUNK], pB[CHUNK];
        auto pf = [&](float* P, int c) {
            #pragma unroll
            for (int i = 0; i < CHUNK; ++i) P[i] = ip[(c * CHUNK + i) * 3 + 0];
        };
        auto cw = [&](const float* P, int c) {
            #pragma unroll
            for (int i = 0; i < CHUNK; ++i) {
                const float p = P[i];
                const float e4  = ex2(-L2E10 * s4);
                const float e4s = ex2c(fmaf(-L2E10, s4, c_4s));
                const float R4  = rcpf((1.0f + e4) * (1.0f + e4s));
                const float E4  = ex2(fmaf(fE, s4, c_E4));
                const float pl  = p * fmaf(p, Kn_, Kl_);
                const float qslow = R4 * fmaf(e4s * E4, pl, qgmax_);
                s4 += clip1e5(qslow);
                op[(c * CHUNK + i) * 5 + 4] = s4;
            }
        };
        pf(pA, 0);
        for (int c = 0; c < NCHUNK; c += 2) {
            pf(pB, c + 1);
            cw(pA, c);
            __builtin_amdgcn_s_barrier();
            if (c + 2 < NCHUNK) pf(pA, c + 2);
            cw(pB, c + 1);
            __builtin_amdgcn_s_barrier();
        }
    }
}

extern "C" void kernel_launch(void* const* d_in, const int* in_sizes, int n_in,
                              void* d_out, int out_size, void* d_ws, size_t ws_size,
                              hipStream_t stream) {
    const float* inp   = (const float*)d_in[0];
    const float* theta = (const float*)d_in[1];
    float* out = (float*)d_out;
    prnn_kernel<<<NB / 64, 256, 0, stream>>>(inp, theta, out);
}

// Round 6
// 559.389 us; speedup vs baseline: 1.5436x; 1.5436x over previous
//
#include <hip/hip_runtime.h>

// PRNNLayer: B=4096 chains x T=2048 steps, 5 states.
// R8: R6's proven structure (role decomposition, SoA plane stores to
// workspace, final transpose, NO barriers) with ONE ROLE PER BLOCK.
// Evidence: per-step cost is ~invariant to instruction count (R0 25 trans:
// 700 cyc/step; R1 17: 654; R6 role1 11: 597) -> ~550 cyc/step fixed floor.
// Candidate: I$ thrash -- all four ~13KB unrolled role bodies shared one CU's
// 32KB I$ in R4-R7. Fix: 256 blocks x 64 threads, role = blockIdx.x & 3, so
// each CU hosts one wave running one variant (fits I$), 256 CUs active.
// Roles write private planes; placement can't cause write amplification.
// All state-update arithmetic verbatim from the verified R5/R6/R7 kernels.

#define NB 4096
#define NT 2048
#define CHUNK 16
#define NCHUNK (NT / CHUNK)  // 128
#define BT ((size_t)NB * (size_t)NT)

#define L2E10 14.4269504089f  // 10*log2(e)  (hv(x) = sigmoid(10x))
#define L2E    1.44269504089f

__device__ __forceinline__ float rcpf(float x) { return __builtin_amdgcn_rcpf(x); }
__device__ __forceinline__ float ex2(float a)  { return __builtin_amdgcn_exp2f(a); }
__device__ __forceinline__ float ex2c(float a) { return __builtin_amdgcn_exp2f(fminf(a, 80.0f)); }
__device__ __forceinline__ float clip1e5(float x) {
    return __builtin_amdgcn_fmed3f(x, -100000.0f, 100000.0f);
}

__global__ __launch_bounds__(64, 1)
void prnn_roles(const float* __restrict__ inp, const float* __restrict__ theta,
                float* __restrict__ out, float* __restrict__ wsp, int use_ws) {
    const int lane = threadIdx.x;
    const int role = blockIdx.x & 3;
    const int b = (blockIdx.x >> 2) * 64 + lane;

    // ---- theta (uniform); each role uses a subset, rest DCE'd ----
    const float f_     = theta[0] * 0.1f;
    const float smax_  = theta[1] * 1950.0f;
    const float qmax_  = theta[2] * 50.0f;
    const float ddf_   = theta[3] * 5.0f;
    const float tmin_  = theta[4] * -3.0f;
    const float tmax_  = theta[5] * 3.0f;
    const float Kc_    = theta[6] * 0.5f;
    const float SCmax_ = theta[7] * 1.5f;
    const float spmax_ = theta[8] * 1950.0f;
    const float qpmax_ = theta[9] * 40.0f;
    const float kp     = theta[10];
    const float sgmax_ = theta[11] * 1950.0f;
    const float qgmax_ = theta[12] * 40.0f;
    const float Kl_    = theta[13] * 0.5f;
    const float Kn_    = theta[14] * 0.5f;

    const float inv_smax = rcpf(smax_);
    const float KcDc  = Kc_ * 0.849932f;          // Kc_ * 0.986*0.862
    const float c_sn  = -L2E10 * tmin_;
    const float c_m   =  L2E10 * tmax_;
    const float c_dd  = -ddf_ * tmax_;
    const float c_sc1 =  L2E10 * SCmax_ * 1.4f;
    const float c_sc0 =  L2E10 * SCmax_ * 0.6f;
    const float c_2p  =  L2E10 * spmax_;
    const float c_3s  =  L2E10 * smax_;
    const float c_4s  =  L2E10 * sgmax_;
    const float fE    = f_ * L2E;
    const float c_E2  = -fE * spmax_;
    const float c_E3  = -fE * smax_;
    const float c_E4  = -fE * sgmax_;

    const float* ip = inp + (size_t)b * (NT * 3);
    float*       op = out + (size_t)b * (NT * 5);
    float* wbase = use_ws ? wsp : out;   // avoid null arith when no ws

    // plane store: one full 64B line per chunk per lane
    auto plane_store = [&](float* plane, const float* ob, int c) {
        float4* d = (float4*)(plane + (size_t)c * CHUNK);
        const float4* s = (const float4*)ob;
        #pragma unroll
        for (int i = 0; i < CHUNK / 4; ++i) d[i] = s[i];
    };

    if (role == 0) {
        // ---- s0 ----
        float s0 = 0.f;
        float bA[CHUNK * 3], bB[CHUNK * 3];
        float* w0 = wbase + 0 * BT + (size_t)b * NT;
        auto pf = [&](float* d, int c) {
            const float4* s = (const float4*)(ip + (size_t)c * (CHUNK * 3));
            #pragma unroll
            for (int i = 0; i < (CHUNK * 3) / 4; ++i) ((float4*)d)[i] = s[i];
        };
        auto cw = [&](const float* d, int c) {
            float ob[CHUNK];
            #pragma unroll
            for (int i = 0; i < CHUNK; ++i) {
                const float p  = d[i * 3 + 0];
                const float dl = d[i * 3 + 2];
                const float day = rcpf(1.0f + ex2(fmaf(-L2E10, dl, 7.21347520f)));
                const float da  = 1.0f + ex2(fmaf(-L2E10, p, L2E));
                const float lai   = fmaf(0.328f, day, 0.15f);
                const float kcf   = fmaf(0.6f, day, 0.4f);
                const float kterm = KcDc * kcf * lai;
                const float zday  = fmaf(c_sc1, day, c_sc0);
                const float e0  = ex2(-L2E10 * s0);
                const float esc = ex2(fmaf(-L2E10, s0, zday));
                const float d0  = 1.0f + e0;
                const float dsc = 1.0f + esc;
                const float Rp  = rcpf(da * d0 * dsc);
                const float pintc = Rp * fmaf(d0 * esc, kterm, p);
                s0 += clip1e5(pintc);
                ob[i] = s0;
            }
            if (use_ws) plane_store(w0, ob, c);
            else {
                #pragma unroll
                for (int i = 0; i < CHUNK; ++i) op[(c * CHUNK + i) * 5 + 0] = ob[i];
            }
        };
        pf(bA, 0);
        for (int c = 0; c < NCHUNK; c += 2) {
            pf(bB, c + 1);
            cw(bA, c);
            if (c + 2 < NCHUNK) pf(bA, c + 2);
            cw(bB, c + 1);
        }
    } else if (role == 1) {
        // ---- s1 + s3 (critical role) ----
        float s1 = 0.f, s3 = 0.f;
        float bA[CHUNK * 3], bB[CHUNK * 3];
        float* w1 = wbase + 1 * BT + (size_t)b * NT;
        float* w3 = wbase + 3 * BT + (size_t)b * NT;
        auto pf = [&](float* d, int c) {
            const float4* s = (const float4*)(ip + (size_t)c * (CHUNK * 3));
            #pragma unroll
            for (int i = 0; i < (CHUNK * 3) / 4; ++i) ((float4*)d)[i] = s[i];
        };
        auto cw = [&](const float* d, int c) {
            float ob1[CHUNK], ob3[CHUNK];
            #pragma unroll
            for (int i = 0; i < CHUNK; ++i) {
                const float p  = d[i * 3 + 0];
                const float tm = d[i * 3 + 1];
                const float dl = d[i * 3 + 2];
                const float A1 = tm + 237.3f;
                const float A2 = tm + 273.2f;
                const float q  = rcpf(A1 * A2);
                const float pe = 436.98672f * dl * ex2(24.958624f * tm * (q * A2)) * (q * A1);
                const float psnow = rcpf(1.0f + ex2(fmaf(L2E10, tm, c_sn))) * p;
                const float dm = 1.0f + ex2(fmaf(-L2E10, tm, c_m));
                const float prain = p - psnow;
                const float e1 = ex2(-L2E10 * s1);
                const float melt = rcpf(dm * (1.0f + e1))
                                   * fminf(s1, fmaf(ddf_, tm, c_dd));
                const float e3  = ex2(-L2E10 * s3);
                const float e3s = ex2c(fmaf(-L2E10, s3, c_3s));
                const float R3  = rcpf((1.0f + e3) * (1.0f + e3s));
                const float E3  = ex2(fmaf(fE, s3, c_E3));
                const float t_et = pe * fmaf(e3s * s3, inv_smax, 1.0f);
                const float t_qs = qmax_ * fmaf(e3s, E3, 1.0f);
                const float outflux = R3 * (t_et + t_qs + (s3 - smax_));
                const float ds3 = prain + melt - outflux;
                s1 += clip1e5(psnow - melt);
                s3 += clip1e5(ds3);
                ob1[i] = s1;
                ob3[i] = s3;
            }
            if (use_ws) { plane_store(w1, ob1, c); plane_store(w3, ob3, c); }
            else {
                #pragma unroll
                for (int i = 0; i < CHUNK; ++i) {
                    op[(c * CHUNK + i) * 5 + 1] = ob1[i];
                    op[(c * CHUNK + i) * 5 + 3] = ob3[i];
                }
            }
        };
        pf(bA, 0);
        for (int c = 0; c < NCHUNK; c += 2) {
            pf(bB, c + 1);
            cw(bA, c);
            if (c + 2 < NCHUNK) pf(bA, c + 2);
            cw(bB, c + 1);
        }
    } else if (role == 2) {
        // ---- s2 ----
        float s2 = 0.f;
        float pA[CHUNK], pB[CHUNK];
        float* w2 = wbase + 2 * BT + (size_t)b * NT;
        auto pf = [&](float* P, int c) {
            #pragma unroll
            for (int i = 0; i < CHUNK; ++i) P[i] = ip[(c * CHUNK + i) * 3 + 0];
        };
        auto cw = [&](const float* P, int c) {
            float ob[CHUNK];
            #pragma unroll
            for (int i = 0; i < CHUNK; ++i) {
                const float p = P[i];
                const float e2  = ex2(-L2E10 * s2);
                const float e2p = ex2c(fmaf(-L2E10, s2, c_2p));
                const float R2  = rcpf((1.0f + e2) * (1.0f + e2p));
                const float E2  = ex2(fmaf(fE, s2, c_E2));
                const float qpref = R2 * fmaf(e2p * E2, kp * p, qpmax_);
                s2 += clip1e5(qpref);
                ob[i] = s2;
            }
            if (use_ws) plane_store(w2, ob, c);
            else {
                #pragma unroll
                for (int i = 0; i < CHUNK; ++i) op[(c * CHUNK + i) * 5 + 2] = ob[i];
            }
        };
        pf(pA, 0);
        for (int c = 0; c < NCHUNK; c += 2) {
            pf(pB, c + 1);
            cw(pA, c);
            if (c + 2 < NCHUNK) pf(pA, c + 2);
            cw(pB, c + 1);
        }
    } else {
        // ---- s4 ----
        float s4 = 0.f;
        float pA[CHUNK], pB[CHUNK];
        float* w4 = wbase + 4 * BT + (size_t)b * NT;
        auto pf = [&](float* P, int c) {
            #pragma unroll
            for (int i = 0; i < CHUNK; ++i) P[i] = ip[(c * CHUNK + i) * 3 + 0];
        };
        auto cw = [&](const float* P, int c) {
            float ob[CHUNK];
            #pragma unroll
            for (int i = 0; i < CHUNK; ++i) {
                const float p = P[i];
                const float e4  = ex2(-L2E10 * s4);
                const float e4s = ex2c(fmaf(-L2E10, s4, c_4s));
                const float R4  = rcpf((1.0f + e4) * (1.0f + e4s));
                const float E4  = ex2(fmaf(fE, s4, c_E4));
                const float pl  = p * fmaf(p, Kn_, Kl_);
                const float qslow = R4 * fmaf(e4s * E4, pl, qgmax_);
                s4 += clip1e5(qslow);
                ob[i] = s4;
            }
            if (use_ws) plane_store(w4, ob, c);
            else {
                #pragma unroll
                for (int i = 0; i < CHUNK; ++i) op[(c * CHUNK + i) * 5 + 4] = ob[i];
            }
        };
        pf(pA, 0);
        for (int c = 0; c < NCHUNK; c += 2) {
            pf(pB, c + 1);
            cw(pA, c);
            if (c + 2 < NCHUNK) pf(pA, c + 2);
            cw(pB, c + 1);
        }
    }
}

// ---- SoA planes -> AoS out. One thread per 4 timesteps of one chain. ----
__global__ __launch_bounds__(256)
void tx_kernel(const float* __restrict__ wsp, float* __restrict__ out) {
    const size_t idx = (size_t)blockIdx.x * 256 + threadIdx.x;  // BT/4 threads
    const size_t b  = idx / (NT / 4);
    const size_t t0 = (idx % (NT / 4)) * 4;
    const float* base = wsp + b * NT + t0;
    const float4 v0 = *(const float4*)(base + 0 * BT);
    const float4 v1 = *(const float4*)(base + 1 * BT);
    const float4 v2 = *(const float4*)(base + 2 * BT);
    const float4 v3 = *(const float4*)(base + 3 * BT);
    const float4 v4 = *(const float4*)(base + 4 * BT);
    float4* o = (float4*)(out + (b * NT + t0) * 5);
    o[0] = make_float4(v0.x, v1.x, v2.x, v3.x);
    o[1] = make_float4(v4.x, v0.y, v1.y, v2.y);
    o[2] = make_float4(v3.y, v4.y, v0.z, v1.z);
    o[3] = make_float4(v2.z, v3.z, v4.z, v0.w);
    o[4] = make_float4(v1.w, v2.w, v3.w, v4.w);
}

extern "C" void kernel_launch(void* const* d_in, const int* in_sizes, int n_in,
                              void* d_out, int out_size, void* d_ws, size_t ws_size,
                              hipStream_t stream) {
    const float* inp   = (const float*)d_in[0];
    const float* theta = (const float*)d_in[1];
    float* out = (float*)d_out;
    float* wsp = (float*)d_ws;
    const int use_ws = (wsp != nullptr && ws_size >= 5 * sizeof(float) * BT) ? 1 : 0;
    prnn_roles<<<4 * (NB / 64), 64, 0, stream>>>(inp, theta, out, wsp, use_ws);
    if (use_ws)
        tx_kernel<<<(int)(BT / 4 / 256), 256, 0, stream>>>(wsp, out);
}